// Round 10
// baseline (743.884 us; speedup 1.0000x reference)
//
#include <hip/hip_runtime.h>

#define DIN   128
#define DMID  256
#define DOUT  128
#define VNUM  50000

typedef __attribute__((ext_vector_type(8))) __bf16 bf16x8;
typedef __attribute__((ext_vector_type(4))) float  f32x4;

// ---- conversions (native HW cvt, RNE) ----
static __device__ __forceinline__ unsigned short b16(float f) {
  union { __bf16 b; unsigned short u; } r; r.b = (__bf16)f; return r.u;
}
static __device__ __forceinline__ unsigned pk2(float lo, float hi) {
  union { __bf16 b[2]; unsigned u; } r;
  r.b[0] = (__bf16)lo; r.b[1] = (__bf16)hi;
  return r.u;
}
// ---- order-preserving monotone maps ----
static __device__ __forceinline__ unsigned unflip_bits(unsigned m) {
  unsigned mask = ((int)m < 0) ? 0x80000000u : 0xFFFFFFFFu;
  return m ^ mask;
}
// flipped u16 -> flipped u32 of same bf16 widened to f32
static __device__ __forceinline__ unsigned flip32_from16(unsigned m) {
  return (m << 16) | ((m & 0x8000u) ? 0u : 0xFFFFu);
}

// ---------------------------------------------------------------------------
// Sort machinery: hist -> (3-kernel multi-block scan) -> scatter
// ---------------------------------------------------------------------------
__global__ void k_hist(const int* __restrict__ vid, int* __restrict__ counts, int E) {
  int i = blockIdx.x * blockDim.x + threadIdx.x;
  if (i < E) atomicAdd(counts + vid[i], 1);
}

__global__ __launch_bounds__(256) void k_scan_red(
    const int* __restrict__ cnt, int* __restrict__ bsum, int V) {
  __shared__ int ws[4];
  const int i = blockIdx.x * 256 + threadIdx.x;
  int c = (i < V) ? cnt[i] : 0;
#pragma unroll
  for (int d = 1; d < 64; d <<= 1) c += __shfl_xor(c, d);
  if ((threadIdx.x & 63) == 0) ws[threadIdx.x >> 6] = c;
  __syncthreads();
  if (threadIdx.x == 0) bsum[blockIdx.x] = ws[0] + ws[1] + ws[2] + ws[3];
}

__global__ __launch_bounds__(256) void k_scan_top(int* __restrict__ bsum, int nb) {
  __shared__ int ws[4];
  const int tid = threadIdx.x, lane = tid & 63, wv = tid >> 6;
  int c = (tid < nb) ? bsum[tid] : 0;
  int s = c;
#pragma unroll
  for (int d = 1; d < 64; d <<= 1) {
    int u = __shfl_up(s, d, 64);
    if (lane >= d) s += u;
  }
  if (lane == 63) ws[wv] = s;
  __syncthreads();
  int off = 0;
  for (int k = 0; k < wv; ++k) off += ws[k];
  if (tid < nb) bsum[tid] = off + (s - c);
}

__global__ __launch_bounds__(256) void k_scan_fix(
    int* __restrict__ cursor, const int* __restrict__ bsum, int V) {
  __shared__ int ws[4];
  const int i = blockIdx.x * 256 + threadIdx.x;
  const int lane = threadIdx.x & 63, wv = threadIdx.x >> 6;
  int c = (i < V) ? cursor[i] : 0;
  int s = c;
#pragma unroll
  for (int d = 1; d < 64; d <<= 1) {
    int u = __shfl_up(s, d, 64);
    if (lane >= d) s += u;
  }
  if (lane == 63) ws[wv] = s;
  __syncthreads();
  int off = bsum[blockIdx.x];
  for (int k = 0; k < wv; ++k) off += ws[k];
  if (i < V) cursor[i] = off + (s - c);
}

__global__ void k_scatter(const int* __restrict__ vid, int* __restrict__ cursor,
                          int* __restrict__ sorted, int E) {
  int i = blockIdx.x * blockDim.x + threadIdx.x;
  if (i < E) {
    int v = vid[i];
    int p = atomicAdd(cursor + v, 1);
    sorted[p] = i;
  }
}

// ---------------------------------------------------------------------------
// Kernel 1: GEMM1 over sorted edges + segmented max.
// RETILED for occupancy (r9 lesson: k1 is concurrency-starved, not BW-bound):
//   tile = 64 edges x 64 cols; block = 256 thr (4 waves of 32r x 32c);
//   4 col-slice blocks (blockIdx&3) cover the 256 cols of each edge tile and
//   share the tile's x rows via L2/L3 (launch-adjacent).
//   VGPR ~90 (acc 16 + bfrag 32 + a 8), LDS ~26KB -> ~5 blocks/CU resident,
//   so gather latency + barrier drains overlap ACROSS blocks.
// NOTE: NO min-waves hint (r5/r6: hints force spill-to-scratch).
// ---------------------------------------------------------------------------
__global__ __launch_bounds__(256) void k_gemm1_max(
    const float* __restrict__ x, const int* __restrict__ vid,
    const int* __restrict__ sorted, const float* __restrict__ W1,
    const float* __restrict__ b1, unsigned* __restrict__ zu, int ntiles) {
  __shared__ unsigned short lx[64 * 132];   // x tile bf16 (row-major, pad 132)
  __shared__ unsigned short zt[64 * 68];    // z slice, flipped bf16, [col][row]
  __shared__ int lvid[64];

  const int tid  = threadIdx.x;
  const int lane = tid & 63;
  const int w    = tid >> 6;       // 0..3
  const int wr   = w & 1;          // row half  (32 rows)
  const int wc   = w >> 1;         // col half  (32 cols)
  const int l15  = lane & 15;
  const int l4   = lane >> 4;
  const int row4 = tid >> 2;       // staging: 4 threads per row, 32 f32 each
  const int s4   = tid & 3;
  const int colbase = (blockIdx.x & 3) * 64;     // this block's 64-col slice
  const int tstep   = gridDim.x >> 2;

  // W1 fragments + bias for this wave's 32 cols
  bf16x8 bfrag[4][2];
  float  bias[2];
#pragma unroll
  for (int ni = 0; ni < 2; ++ni) {
    const int col = colbase + wc * 32 + ni * 16 + l15;
    bias[ni] = b1[col];
#pragma unroll
    for (int kk = 0; kk < 4; ++kk) {
      union { bf16x8 v; unsigned short u[8]; } tmp;
#pragma unroll
      for (int j = 0; j < 8; ++j)
        tmp.u[j] = b16(W1[(kk * 32 + l4 * 8 + j) * DMID + col]);
      bfrag[kk][ni] = tmp.v;
    }
  }

  for (int t = blockIdx.x >> 2; t < ntiles; t += tstep) {
    // ---- stage x tile (gather) + vids ----
    if (tid < 64) lvid[tid] = vid[sorted[t * 64 + tid]];
    {
      const int eid = sorted[t * 64 + row4];
      const float4* src =
          reinterpret_cast<const float4*>(x + (size_t)eid * DIN + s4 * 32);
      unsigned short* dst = &lx[row4 * 132 + s4 * 32];
#pragma unroll
      for (int i = 0; i < 8; ++i) {
        float4 v = src[i];
        uint2 o = { pk2(v.x, v.y), pk2(v.z, v.w) };
        *reinterpret_cast<uint2*>(dst + i * 4) = o;
      }
    }
    __syncthreads();

    // uniform run-end mask (bit r = row r ends a vid run); identical per wave
    const int myv = lvid[lane];
    const int nv  = (lane == 63) ? (myv ^ 1) : lvid[lane + 1];
    const unsigned long long emask = __ballot(myv != nv);

    // ---- MFMA: 32 rows x 32 cols per wave, K=128 ----
    f32x4 acc[2][2];
#pragma unroll
    for (int mi = 0; mi < 2; ++mi)
#pragma unroll
      for (int ni = 0; ni < 2; ++ni)
        acc[mi][ni] = (f32x4){bias[ni], bias[ni], bias[ni], bias[ni]};
#pragma unroll
    for (int kk = 0; kk < 4; ++kk) {
      bf16x8 a[2];
#pragma unroll
      for (int mi = 0; mi < 2; ++mi)
        a[mi] = *reinterpret_cast<const bf16x8*>(
            &lx[(wr * 32 + mi * 16 + l15) * 132 + kk * 32 + l4 * 8]);
#pragma unroll
      for (int mi = 0; mi < 2; ++mi)
#pragma unroll
        for (int ni = 0; ni < 2; ++ni)
          acc[mi][ni] = __builtin_amdgcn_mfma_f32_16x16x32_bf16(
              a[mi], bfrag[kk][ni], acc[mi][ni], 0, 0, 0);
    }

    // ---- pack acc -> zt (flipped bf16, [col][row], stride 68 shorts) ----
    {
      unsigned* ztw = reinterpret_cast<unsigned*>(zt);
#pragma unroll
      for (int ni = 0; ni < 2; ++ni) {
        const int colb = wc * 32 + ni * 16 + l15;   // col within slice
        const int cb = colb * 34 + wr * 16 + l4 * 2;
#pragma unroll
        for (int mi = 0; mi < 2; ++mi)
#pragma unroll
          for (int p = 0; p < 2; ++p) {
            unsigned tpk = pk2(acc[mi][ni][2 * p], acc[mi][ni][2 * p + 1]);
            unsigned mflip = 0x80008000u + ((tpk >> 15) & 0x00010001u) * 0x7FFFu;
            ztw[cb + mi * 8 + p] = tpk ^ mflip;
          }
      }
    }
    __syncthreads();

    // ---- walk: 4 threads per column (16 rows each) ----
    {
      const int c64 = tid & 63;           // col within slice
      const int q   = tid >> 6;           // quarter 0..3
      const int col = colbase + c64;      // global col
      const unsigned* zc =
          reinterpret_cast<const unsigned*>(&zt[c64 * 68 + q * 16]);
      unsigned cur = 0;
      bool first = true;
      const bool extL = (q == 0) ? true : (lvid[q * 16 - 1] == lvid[q * 16]);
#pragma unroll
      for (int p = 0; p < 8; ++p) {
        const unsigned pr = zc[p];
#pragma unroll
        for (int j = 0; j < 2; ++j) {
          const unsigned val = j ? (pr >> 16) : (pr & 0xFFFFu);
          cur = val > cur ? val : cur;
          const int row = q * 16 + p * 2 + j;
          if ((emask >> row) & 1) {
            const unsigned enc = flip32_from16(cur);
            unsigned* ad = zu + (size_t)lvid[row] * DMID + col;
            // atomic iff run extends beyond this quarter/tile edge
            if ((first && extL) || row == 63) atomicMax(ad, enc);
            else *ad = enc;
            cur = 0; first = false;
          }
        }
      }
      if (!((emask >> (q * 16 + 15)) & 1))  // open run continues past quarter
        atomicMax(zu + (size_t)lvid[q * 16 + 15] * DMID + col,
                  flip32_from16(cur));
    }
    __syncthreads();
  }
}

// ---------------------------------------------------------------------------
// Kernel Y: Y = unflip(zu) @ W2b  (V x 128). Block 256, wave 2x2.
// ---------------------------------------------------------------------------
__global__ __launch_bounds__(256) void k_ymm(
    const unsigned* __restrict__ zu, const float* __restrict__ W2,
    float* __restrict__ Y, int ntiles) {
  extern __shared__ unsigned short sm[];
  unsigned short* w2bt = sm;               // [128][264]
  unsigned short* za   = sm + 128 * 264;   // [64][264]

  const int tid  = threadIdx.x;
  const int lane = tid & 63;
  const int w    = tid >> 6;
  const int wr   = w >> 1, wc = w & 1;
  const int l15  = lane & 15, l4 = lane >> 4;

  {
    const int n = tid & 127, kh = tid >> 7;
    for (int k = kh * 128; k < kh * 128 + 128; ++k)
      w2bt[n * 264 + k] = b16(W2[(size_t)(DIN + k) * DOUT + n]);
  }
  __syncthreads();

  for (int t = blockIdx.x; t < ntiles; t += gridDim.x) {
    {
      const int row = tid >> 2, q = tid & 3;
      const int v = t * 64 + row;
      unsigned short* dz = &za[row * 264 + q * 64];
      if (v < VNUM) {
        const uint4* sz = reinterpret_cast<const uint4*>(zu + (size_t)v * DMID + q * 64);
#pragma unroll
        for (int i = 0; i < 16; ++i) {
          uint4 m = sz[i];
          ushort4 o = { (unsigned short)(unflip_bits(m.x) >> 16),
                        (unsigned short)(unflip_bits(m.y) >> 16),
                        (unsigned short)(unflip_bits(m.z) >> 16),
                        (unsigned short)(unflip_bits(m.w) >> 16) };
          *reinterpret_cast<ushort4*>(dz + i * 4) = o;
        }
      } else {
        ushort4 zo = {0, 0, 0, 0};
#pragma unroll
        for (int i = 0; i < 16; ++i) *reinterpret_cast<ushort4*>(dz + i * 4) = zo;
      }
    }
    __syncthreads();

    f32x4 acc[2][4];
#pragma unroll
    for (int mi = 0; mi < 2; ++mi)
#pragma unroll
      for (int ni = 0; ni < 4; ++ni) acc[mi][ni] = (f32x4){0.f, 0.f, 0.f, 0.f};

#pragma unroll
    for (int kk = 0; kk < 8; ++kk) {
      bf16x8 a[2], b[4];
#pragma unroll
      for (int mi = 0; mi < 2; ++mi)
        a[mi] = *reinterpret_cast<const bf16x8*>(
            &za[(wr * 32 + mi * 16 + l15) * 264 + kk * 32 + l4 * 8]);
#pragma unroll
      for (int ni = 0; ni < 4; ++ni)
        b[ni] = *reinterpret_cast<const bf16x8*>(
            &w2bt[(wc * 64 + ni * 16 + l15) * 264 + kk * 32 + l4 * 8]);
#pragma unroll
      for (int mi = 0; mi < 2; ++mi)
#pragma unroll
        for (int ni = 0; ni < 4; ++ni)
          acc[mi][ni] = __builtin_amdgcn_mfma_f32_16x16x32_bf16(
              a[mi], b[ni], acc[mi][ni], 0, 0, 0);
    }

#pragma unroll
    for (int mi = 0; mi < 2; ++mi)
#pragma unroll
      for (int r = 0; r < 4; ++r) {
        const int v = t * 64 + wr * 32 + mi * 16 + l4 * 4 + r;
        if (v < VNUM) {
          float* o = Y + (size_t)v * DOUT + wc * 64 + l15;
#pragma unroll
          for (int ni = 0; ni < 4; ++ni) o[ni * 16] = acc[mi][ni][r];
        }
      }
    __syncthreads();
  }
}

// ---------------------------------------------------------------------------
// Kernel 2: out = x @ W2a + Y[vid]  (original edge order). Block 256, wave 2x2.
// ---------------------------------------------------------------------------
__global__ __launch_bounds__(256, 3) void k_gemm2(
    const float* __restrict__ x, const int* __restrict__ vid,
    const float* __restrict__ W2, const float* __restrict__ Y,
    float* __restrict__ out, int ntiles) {
  __shared__ unsigned short w2at[128 * 136];
  __shared__ unsigned short lx[64 * 136];
  __shared__ int lvid[64];

  const int tid  = threadIdx.x;
  const int lane = tid & 63;
  const int w    = tid >> 6;
  const int wr   = w >> 1, wc = w & 1;
  const int l15  = lane & 15, l4 = lane >> 4;

  {
    const int n = tid & 127, kh = tid >> 7;
    for (int k = kh * 64; k < kh * 64 + 64; ++k)
      w2at[n * 136 + k] = b16(W2[(size_t)k * DOUT + n]);
  }
  __syncthreads();

  for (int t = blockIdx.x; t < ntiles; t += gridDim.x) {
    {
      const int row = tid >> 2, q = tid & 3;
      const float4* sx =
          reinterpret_cast<const float4*>(x + (size_t)(t * 64 + row) * DIN + q * 32);
#pragma unroll
      for (int i = 0; i < 8; ++i) {
        float4 v = sx[i];
        uint2 o = { pk2(v.x, v.y), pk2(v.z, v.w) };
        *reinterpret_cast<uint2*>(&lx[row * 136 + q * 32 + i * 4]) = o;
      }
      if (tid < 64) lvid[tid] = vid[t * 64 + tid];
    }
    __syncthreads();

    f32x4 acc[2][4];
#pragma unroll
    for (int mi = 0; mi < 2; ++mi)
#pragma unroll
      for (int ni = 0; ni < 4; ++ni) acc[mi][ni] = (f32x4){0.f, 0.f, 0.f, 0.f};

#pragma unroll
    for (int kk = 0; kk < 4; ++kk) {
      bf16x8 a[2], b[4];
#pragma unroll
      for (int mi = 0; mi < 2; ++mi)
        a[mi] = *reinterpret_cast<const bf16x8*>(
            &lx[(wr * 32 + mi * 16 + l15) * 136 + kk * 32 + l4 * 8]);
#pragma unroll
      for (int ni = 0; ni < 4; ++ni)
        b[ni] = *reinterpret_cast<const bf16x8*>(
            &w2at[(wc * 64 + ni * 16 + l15) * 136 + kk * 32 + l4 * 8]);
#pragma unroll
      for (int mi = 0; mi < 2; ++mi)
#pragma unroll
        for (int ni = 0; ni < 4; ++ni)
          acc[mi][ni] = __builtin_amdgcn_mfma_f32_16x16x32_bf16(
              a[mi], b[ni], acc[mi][ni], 0, 0, 0);
    }

    // epilogue: + Y[vid], fp32 store
#pragma unroll
    for (int mi = 0; mi < 2; ++mi)
#pragma unroll
      for (int r = 0; r < 4; ++r) {
        const int row = wr * 32 + mi * 16 + l4 * 4 + r;
        const float* Yr = Y + (size_t)lvid[row] * DOUT + wc * 64 + l15;
        float* o = out + (size_t)(t * 64 + row) * DOUT + wc * 64 + l15;
#pragma unroll
        for (int ni = 0; ni < 4; ++ni) o[ni * 16] = acc[mi][ni][r] + Yr[ni * 16];
      }
    __syncthreads();
  }
}

// ---------------------------------------------------------------------------
extern "C" void kernel_launch(void* const* d_in, const int* in_sizes, int n_in,
                              void* d_out, int out_size, void* d_ws, size_t ws_size,
                              hipStream_t stream) {
  const float* x   = (const float*)d_in[0];
  const int*   vid = (const int*)d_in[1];
  const float* W1  = (const float*)d_in[2];
  const float* b1  = (const float*)d_in[3];
  const float* W2  = (const float*)d_in[4];
  float* out = (float*)d_out;

  const int E = in_sizes[1];      // 800000 (divisible by 64)
  const int ntiles = E / 64;
  const int ntY = (VNUM + 63) / 64;   // 782
  const int nb = (VNUM + 255) / 256;  // 196 scan blocks

  char* ws = (char*)d_ws;
  size_t off = 0;
  unsigned* zu = (unsigned*)(ws + off); off += (size_t)VNUM * DMID * 4;
  int* cnt     = (int*)(ws + off);      off += (size_t)VNUM * 4;
  int* sorted  = (int*)(ws + off);      off += (size_t)E * 4;
  float* Y     = (float*)(ws + off);    off += (size_t)VNUM * DOUT * 4;
  int* bsum    = (int*)(ws + off);      off += 4096;

  hipMemsetAsync(zu, 0, (size_t)VNUM * DMID * 4 + VNUM * 4, stream);

  k_hist<<<(E + 255) / 256, 256, 0, stream>>>(vid, cnt, E);
  k_scan_red<<<nb, 256, 0, stream>>>(cnt, bsum, VNUM);
  k_scan_top<<<1, 256, 0, stream>>>(bsum, nb);
  k_scan_fix<<<nb, 256, 0, stream>>>(cnt, bsum, VNUM);
  k_scatter<<<(E + 255) / 256, 256, 0, stream>>>(vid, cnt, sorted, E);

  // 4096 blocks = 1024 tile-chains x 4 col-slices
  k_gemm1_max<<<4096, 256, 0, stream>>>(x, vid, sorted, W1, b1, zu, ntiles);

  const int smY = (128 * 264 + 64 * 264) * sizeof(unsigned short);
  hipFuncSetAttribute((const void*)k_ymm,
                      hipFuncAttributeMaxDynamicSharedMemorySize, smY);
  k_ymm<<<782, 256, smY, stream>>>(zu, W2, Y, ntY);

  k_gemm2<<<768, 256, 0, stream>>>(x, vid, W2, Y, out, ntiles);
}

// Round 11
// 652.677 us; speedup vs baseline: 1.1397x; 1.1397x over previous
//
#include <hip/hip_runtime.h>

#define DIN   128
#define DMID  256
#define DOUT  128
#define VNUM  50000

typedef __attribute__((ext_vector_type(8))) __bf16 bf16x8;
typedef __attribute__((ext_vector_type(4))) float  f32x4;

// ---- conversions (native HW cvt, RNE) ----
static __device__ __forceinline__ unsigned short b16(float f) {
  union { __bf16 b; unsigned short u; } r; r.b = (__bf16)f; return r.u;
}
static __device__ __forceinline__ unsigned pk2(float lo, float hi) {
  union { __bf16 b[2]; unsigned u; } r;
  r.b[0] = (__bf16)lo; r.b[1] = (__bf16)hi;
  return r.u;
}
// ---- order-preserving monotone maps ----
static __device__ __forceinline__ unsigned unflip_bits(unsigned m) {
  unsigned mask = ((int)m < 0) ? 0x80000000u : 0xFFFFFFFFu;
  return m ^ mask;
}
// flipped u16 -> flipped u32 of same bf16 widened to f32
static __device__ __forceinline__ unsigned flip32_from16(unsigned m) {
  return (m << 16) | ((m & 0x8000u) ? 0u : 0xFFFFu);
}

// ---------------------------------------------------------------------------
// Sort machinery: hist -> multi-block scan -> PERMUTING COPY.
// r10 lesson: k1's wall is the random 512B x-row gather (r2/r7/r8 plateau
// ~250-280us across structures; r9: not DRAM-BW; r10: not occupancy). So the
// random access is moved HERE: a barrier-free streaming kernel writes
// xs[p] = bf16(x[e]) (scattered 256B stores, fire-and-forget) and svid[p]=v.
// k1 then reads xs/svid CONTIGUOUSLY.
// ---------------------------------------------------------------------------
__global__ void k_hist(const int* __restrict__ vid, int* __restrict__ counts, int E) {
  int i = blockIdx.x * blockDim.x + threadIdx.x;
  if (i < E) atomicAdd(counts + vid[i], 1);
}

__global__ __launch_bounds__(256) void k_scan_red(
    const int* __restrict__ cnt, int* __restrict__ bsum, int V) {
  __shared__ int ws[4];
  const int i = blockIdx.x * 256 + threadIdx.x;
  int c = (i < V) ? cnt[i] : 0;
#pragma unroll
  for (int d = 1; d < 64; d <<= 1) c += __shfl_xor(c, d);
  if ((threadIdx.x & 63) == 0) ws[threadIdx.x >> 6] = c;
  __syncthreads();
  if (threadIdx.x == 0) bsum[blockIdx.x] = ws[0] + ws[1] + ws[2] + ws[3];
}

__global__ __launch_bounds__(256) void k_scan_top(int* __restrict__ bsum, int nb) {
  __shared__ int ws[4];
  const int tid = threadIdx.x, lane = tid & 63, wv = tid >> 6;
  int c = (tid < nb) ? bsum[tid] : 0;
  int s = c;
#pragma unroll
  for (int d = 1; d < 64; d <<= 1) {
    int u = __shfl_up(s, d, 64);
    if (lane >= d) s += u;
  }
  if (lane == 63) ws[wv] = s;
  __syncthreads();
  int off = 0;
  for (int k = 0; k < wv; ++k) off += ws[k];
  if (tid < nb) bsum[tid] = off + (s - c);
}

__global__ __launch_bounds__(256) void k_scan_fix(
    int* __restrict__ cursor, const int* __restrict__ bsum, int V) {
  __shared__ int ws[4];
  const int i = blockIdx.x * 256 + threadIdx.x;
  const int lane = threadIdx.x & 63, wv = threadIdx.x >> 6;
  int c = (i < V) ? cursor[i] : 0;
  int s = c;
#pragma unroll
  for (int d = 1; d < 64; d <<= 1) {
    int u = __shfl_up(s, d, 64);
    if (lane >= d) s += u;
  }
  if (lane == 63) ws[wv] = s;
  __syncthreads();
  int off = bsum[blockIdx.x];
  for (int k = 0; k < wv; ++k) off += ws[k];
  if (i < V) cursor[i] = off + (s - c);
}

// 8 threads per edge: leader atomicAdd's the vertex cursor, broadcasts p via
// shfl; group copies the 512B f32 row -> 256B bf16 row at xs[p], svid[p]=v.
__global__ __launch_bounds__(256) void k_scatter_copy(
    const float* __restrict__ x, const int* __restrict__ vid,
    int* __restrict__ cursor, unsigned short* __restrict__ xs,
    int* __restrict__ svid, int E) {
  const int g = blockIdx.x * 256 + threadIdx.x;
  const int e = g >> 3;
  if (e >= E) return;
  const int lane = threadIdx.x & 63;
  const int s8 = g & 7;
  const int v = vid[e];
  int p = 0;
  if (s8 == 0) p = atomicAdd(cursor + v, 1);
  p = __shfl(p, (lane >> 3) << 3, 64);   // broadcast from group leader

  const float4* src = reinterpret_cast<const float4*>(x + (size_t)e * DIN + s8 * 16);
  float4 a = src[0], b = src[1], c = src[2], d = src[3];
  uint4 o0 = { pk2(a.x, a.y), pk2(a.z, a.w), pk2(b.x, b.y), pk2(b.z, b.w) };
  uint4 o1 = { pk2(c.x, c.y), pk2(c.z, c.w), pk2(d.x, d.y), pk2(d.z, d.w) };
  uint4* dst = reinterpret_cast<uint4*>(xs + (size_t)p * DIN + s8 * 16);
  dst[0] = o0; dst[1] = o1;
  if (s8 == 0) svid[p] = v;
}

// ---------------------------------------------------------------------------
// Kernel 1: GEMM1 over PERMUTED xs (contiguous bf16 reads, no gather) +
// segmented max. r8 pipeline skeleton: 2 barriers/tile, next tile's rows
// prefetched to regs during phase 1, written to LDS after the walk.
// NOTE: NO min-waves hint (r5/r6: hints force spill-to-scratch).
// ---------------------------------------------------------------------------
__global__ __launch_bounds__(512) void k_gemm1_max(
    const unsigned short* __restrict__ xs, const int* __restrict__ svid,
    const float* __restrict__ W1, const float* __restrict__ b1,
    unsigned* __restrict__ zu, int ntiles) {
  __shared__ unsigned short lx[64 * 136];   // x tile bf16 (row-major)
  __shared__ unsigned short zt[256 * 70];   // z tile, flipped bf16, [col][row]
  __shared__ int lvid[2][64];

  const int tid  = threadIdx.x;
  const int lane = tid & 63;
  const int w    = tid >> 6;       // 0..7
  const int l15  = lane & 15;
  const int l4   = lane >> 4;
  const int row8 = tid >> 3;       // staging: 8 threads per row, 16 bf16 each
  const int s8   = tid & 7;
  const int G    = gridDim.x;

  // W1 fragments + bias for this wave's 32 cols
  bf16x8 bfrag[4][2];
  float  bias[2];
#pragma unroll
  for (int ni = 0; ni < 2; ++ni) {
    const int col = w * 32 + ni * 16 + l15;
    bias[ni] = b1[col];
#pragma unroll
    for (int kk = 0; kk < 4; ++kk) {
      union { bf16x8 v; unsigned short u[8]; } tmp;
#pragma unroll
      for (int j = 0; j < 8; ++j)
        tmp.u[j] = b16(W1[(kk * 32 + l4 * 8 + j) * DMID + col]);
      bfrag[kk][ni] = tmp.v;
    }
  }

  const int t0 = blockIdx.x;
  if (t0 >= ntiles) return;

  // ---- prologue: stage tile t0 ----
  {
    if (tid < 64) lvid[0][tid] = svid[t0 * 64 + tid];
    const uint4* s =
        reinterpret_cast<const uint4*>(xs + ((size_t)t0 * 64 + row8) * DIN + s8 * 16);
    uint4* dst = reinterpret_cast<uint4*>(&lx[row8 * 136 + s8 * 16]);
    dst[0] = s[0]; dst[1] = s[1];
  }
  __syncthreads();

  int cur = 0;
  for (int t = t0; t < ntiles; t += G, cur ^= 1) {
    const bool more = (t + G) < ntiles;

    // ---- phase 1: issue next tile's row + vid loads (contiguous) ----
    uint4 A0, A1; int vN = 0;
    if (more) {
      const uint4* s = reinterpret_cast<const uint4*>(
          xs + ((size_t)(t + G) * 64 + row8) * DIN + s8 * 16);
      A0 = s[0]; A1 = s[1];
      if (tid < 64) vN = svid[(t + G) * 64 + tid];
    }

    // uniform run-end mask (bit r = row r ends a vid run)
    const int myv = lvid[cur][lane];
    const int nv  = (lane == 63) ? (myv ^ 1) : lvid[cur][lane + 1];
    const unsigned long long emask = __ballot(myv != nv);
    const bool contOpen = (lvid[cur][31] == lvid[cur][32]);

    // ---- MFMA: 64 rows x 32 cols per wave, K=128 ----
    f32x4 acc[4][2];
#pragma unroll
    for (int mi = 0; mi < 4; ++mi)
#pragma unroll
      for (int ni = 0; ni < 2; ++ni)
        acc[mi][ni] = (f32x4){bias[ni], bias[ni], bias[ni], bias[ni]};
#pragma unroll
    for (int kk = 0; kk < 4; ++kk) {
      bf16x8 a[4];
#pragma unroll
      for (int mi = 0; mi < 4; ++mi)
        a[mi] = *reinterpret_cast<const bf16x8*>(
            &lx[(mi * 16 + l15) * 136 + kk * 32 + l4 * 8]);
#pragma unroll
      for (int mi = 0; mi < 4; ++mi)
#pragma unroll
        for (int ni = 0; ni < 2; ++ni)
          acc[mi][ni] = __builtin_amdgcn_mfma_f32_16x16x32_bf16(
              a[mi], bfrag[kk][ni], acc[mi][ni], 0, 0, 0);
    }

    // ---- pack acc -> zt (flipped bf16, column-major) ----
    {
      unsigned* ztw = reinterpret_cast<unsigned*>(zt);
#pragma unroll
      for (int ni = 0; ni < 2; ++ni) {
        const int col = w * 32 + ni * 16 + l15;
        const int cb  = col * 35 + l4 * 2;
#pragma unroll
        for (int mi = 0; mi < 4; ++mi)
#pragma unroll
          for (int p = 0; p < 2; ++p) {
            unsigned tpk = pk2(acc[mi][ni][2 * p], acc[mi][ni][2 * p + 1]);
            unsigned mflip = 0x80008000u + ((tpk >> 15) & 0x00010001u) * 0x7FFFu;
            ztw[cb + mi * 8 + p] = tpk ^ mflip;
          }
      }
    }
    __syncthreads();   // zt visible; lx consumed

    // ---- walk zt(t): 2 threads per column, 32 rows each ----
    {
      const int col = tid & 255;
      const int h   = tid >> 8;
      const unsigned* zc = reinterpret_cast<const unsigned*>(&zt[col * 70 + h * 32]);
      unsigned curm = 0;
      bool first = true;
#pragma unroll
      for (int p = 0; p < 16; ++p) {
        const unsigned pr = zc[p];
#pragma unroll
        for (int j = 0; j < 2; ++j) {
          const unsigned val = j ? (pr >> 16) : (pr & 0xFFFFu);
          curm = val > curm ? val : curm;
          const int row = h * 32 + p * 2 + j;
          if ((emask >> row) & 1) {
            const int v = lvid[cur][row];
            const unsigned enc = flip32_from16(curm);
            unsigned* ad = zu + (size_t)v * DMID + col;
            if (row == 63 || (first && (h == 0 || contOpen))) atomicMax(ad, enc);
            else *ad = enc;
            curm = 0; first = false;
          }
        }
      }
      if (h == 0 && !((emask >> 31) & 1)) {  // trailing open run in top half
        const int v = lvid[cur][31];
        atomicMax(zu + (size_t)v * DMID + col, flip32_from16(curm));
      }
    }

    // ---- write prefetched tile to LDS ----
    if (more) {
      uint4* dst = reinterpret_cast<uint4*>(&lx[row8 * 136 + s8 * 16]);
      dst[0] = A0; dst[1] = A1;
      if (tid < 64) lvid[cur ^ 1][tid] = vN;
    }
    __syncthreads();   // stage visible; walk complete before next pack
  }
}

// ---------------------------------------------------------------------------
// Kernel Y: Y = unflip(zu) @ W2b  (V x 128). Block 256, wave 2x2.
// ---------------------------------------------------------------------------
__global__ __launch_bounds__(256) void k_ymm(
    const unsigned* __restrict__ zu, const float* __restrict__ W2,
    float* __restrict__ Y, int ntiles) {
  extern __shared__ unsigned short sm[];
  unsigned short* w2bt = sm;               // [128][264]
  unsigned short* za   = sm + 128 * 264;   // [64][264]

  const int tid  = threadIdx.x;
  const int lane = tid & 63;
  const int w    = tid >> 6;
  const int wr   = w >> 1, wc = w & 1;
  const int l15  = lane & 15, l4 = lane >> 4;

  {
    const int n = tid & 127, kh = tid >> 7;
    for (int k = kh * 128; k < kh * 128 + 128; ++k)
      w2bt[n * 264 + k] = b16(W2[(size_t)(DIN + k) * DOUT + n]);
  }
  __syncthreads();

  for (int t = blockIdx.x; t < ntiles; t += gridDim.x) {
    {
      const int row = tid >> 2, q = tid & 3;
      const int v = t * 64 + row;
      unsigned short* dz = &za[row * 264 + q * 64];
      if (v < VNUM) {
        const uint4* sz = reinterpret_cast<const uint4*>(zu + (size_t)v * DMID + q * 64);
#pragma unroll
        for (int i = 0; i < 16; ++i) {
          uint4 m = sz[i];
          ushort4 o = { (unsigned short)(unflip_bits(m.x) >> 16),
                        (unsigned short)(unflip_bits(m.y) >> 16),
                        (unsigned short)(unflip_bits(m.z) >> 16),
                        (unsigned short)(unflip_bits(m.w) >> 16) };
          *reinterpret_cast<ushort4*>(dz + i * 4) = o;
        }
      } else {
        ushort4 zo = {0, 0, 0, 0};
#pragma unroll
        for (int i = 0; i < 16; ++i) *reinterpret_cast<ushort4*>(dz + i * 4) = zo;
      }
    }
    __syncthreads();

    f32x4 acc[2][4];
#pragma unroll
    for (int mi = 0; mi < 2; ++mi)
#pragma unroll
      for (int ni = 0; ni < 4; ++ni) acc[mi][ni] = (f32x4){0.f, 0.f, 0.f, 0.f};

#pragma unroll
    for (int kk = 0; kk < 8; ++kk) {
      bf16x8 a[2], b[4];
#pragma unroll
      for (int mi = 0; mi < 2; ++mi)
        a[mi] = *reinterpret_cast<const bf16x8*>(
            &za[(wr * 32 + mi * 16 + l15) * 264 + kk * 32 + l4 * 8]);
#pragma unroll
      for (int ni = 0; ni < 4; ++ni)
        b[ni] = *reinterpret_cast<const bf16x8*>(
            &w2bt[(wc * 64 + ni * 16 + l15) * 264 + kk * 32 + l4 * 8]);
#pragma unroll
      for (int mi = 0; mi < 2; ++mi)
#pragma unroll
        for (int ni = 0; ni < 4; ++ni)
          acc[mi][ni] = __builtin_amdgcn_mfma_f32_16x16x32_bf16(
              a[mi], b[ni], acc[mi][ni], 0, 0, 0);
    }

#pragma unroll
    for (int mi = 0; mi < 2; ++mi)
#pragma unroll
      for (int r = 0; r < 4; ++r) {
        const int v = t * 64 + wr * 32 + mi * 16 + l4 * 4 + r;
        if (v < VNUM) {
          float* o = Y + (size_t)v * DOUT + wc * 64 + l15;
#pragma unroll
          for (int ni = 0; ni < 4; ++ni) o[ni * 16] = acc[mi][ni][r];
        }
      }
    __syncthreads();
  }
}

// ---------------------------------------------------------------------------
// Kernel 2: out = x @ W2a + Y[vid]  (original edge order). Block 256, wave 2x2.
// ---------------------------------------------------------------------------
__global__ __launch_bounds__(256, 3) void k_gemm2(
    const float* __restrict__ x, const int* __restrict__ vid,
    const float* __restrict__ W2, const float* __restrict__ Y,
    float* __restrict__ out, int ntiles) {
  __shared__ unsigned short w2at[128 * 136];
  __shared__ unsigned short lx[64 * 136];
  __shared__ int lvid[64];

  const int tid  = threadIdx.x;
  const int lane = tid & 63;
  const int w    = tid >> 6;
  const int wr   = w >> 1, wc = w & 1;
  const int l15  = lane & 15, l4 = lane >> 4;

  {
    const int n = tid & 127, kh = tid >> 7;
    for (int k = kh * 64; k < kh * 64 + 64; ++k)
      w2at[n * 136 + k] = b16(W2[(size_t)k * DOUT + n]);
  }
  __syncthreads();

  for (int t = blockIdx.x; t < ntiles; t += gridDim.x) {
    {
      const int row = tid >> 2, q = tid & 3;
      const float4* sx =
          reinterpret_cast<const float4*>(x + (size_t)(t * 64 + row) * DIN + q * 32);
#pragma unroll
      for (int i = 0; i < 8; ++i) {
        float4 v = sx[i];
        uint2 o = { pk2(v.x, v.y), pk2(v.z, v.w) };
        *reinterpret_cast<uint2*>(&lx[row * 136 + q * 32 + i * 4]) = o;
      }
      if (tid < 64) lvid[tid] = vid[t * 64 + tid];
    }
    __syncthreads();

    f32x4 acc[2][4];
#pragma unroll
    for (int mi = 0; mi < 2; ++mi)
#pragma unroll
      for (int ni = 0; ni < 4; ++ni) acc[mi][ni] = (f32x4){0.f, 0.f, 0.f, 0.f};

#pragma unroll
    for (int kk = 0; kk < 4; ++kk) {
      bf16x8 a[2], b[4];
#pragma unroll
      for (int mi = 0; mi < 2; ++mi)
        a[mi] = *reinterpret_cast<const bf16x8*>(
            &lx[(wr * 32 + mi * 16 + l15) * 136 + kk * 32 + l4 * 8]);
#pragma unroll
      for (int ni = 0; ni < 4; ++ni)
        b[ni] = *reinterpret_cast<const bf16x8*>(
            &w2at[(wc * 64 + ni * 16 + l15) * 136 + kk * 32 + l4 * 8]);
#pragma unroll
      for (int mi = 0; mi < 2; ++mi)
#pragma unroll
        for (int ni = 0; ni < 4; ++ni)
          acc[mi][ni] = __builtin_amdgcn_mfma_f32_16x16x32_bf16(
              a[mi], b[ni], acc[mi][ni], 0, 0, 0);
    }

    // epilogue: + Y[vid], fp32 store
#pragma unroll
    for (int mi = 0; mi < 2; ++mi)
#pragma unroll
      for (int r = 0; r < 4; ++r) {
        const int row = wr * 32 + mi * 16 + l4 * 4 + r;
        const float* Yr = Y + (size_t)lvid[row] * DOUT + wc * 64 + l15;
        float* o = out + (size_t)(t * 64 + row) * DOUT + wc * 64 + l15;
#pragma unroll
        for (int ni = 0; ni < 4; ++ni) o[ni * 16] = acc[mi][ni][r] + Yr[ni * 16];
      }
    __syncthreads();
  }
}

// ---------------------------------------------------------------------------
extern "C" void kernel_launch(void* const* d_in, const int* in_sizes, int n_in,
                              void* d_out, int out_size, void* d_ws, size_t ws_size,
                              hipStream_t stream) {
  const float* x   = (const float*)d_in[0];
  const int*   vid = (const int*)d_in[1];
  const float* W1  = (const float*)d_in[2];
  const float* b1  = (const float*)d_in[3];
  const float* W2  = (const float*)d_in[4];
  float* out = (float*)d_out;

  const int E = in_sizes[1];      // 800000 (divisible by 64)
  const int ntiles = E / 64;
  const int ntY = (VNUM + 63) / 64;   // 782
  const int nb = (VNUM + 255) / 256;  // 196 scan blocks

  char* ws = (char*)d_ws;
  size_t off = 0;
  unsigned* zu = (unsigned*)(ws + off); off += (size_t)VNUM * DMID * 4;
  int* cnt     = (int*)(ws + off);      off += (size_t)VNUM * 4;
  float* Y     = (float*)(ws + off);    off += (size_t)VNUM * DOUT * 4;
  int* bsum    = (int*)(ws + off);      off += 4096;
  int* svid    = (int*)(ws + off);      off += (size_t)E * 4;
  unsigned short* xs = (unsigned short*)(ws + off);  // E*128 bf16 = 204.8MB

  hipMemsetAsync(zu, 0, (size_t)VNUM * DMID * 4 + VNUM * 4, stream);

  k_hist<<<(E + 255) / 256, 256, 0, stream>>>(vid, cnt, E);
  k_scan_red<<<nb, 256, 0, stream>>>(cnt, bsum, VNUM);
  k_scan_top<<<1, 256, 0, stream>>>(bsum, nb);
  k_scan_fix<<<nb, 256, 0, stream>>>(cnt, bsum, VNUM);
  // permuting copy: x (f32, original order) -> xs (bf16, vertex-sorted)
  k_scatter_copy<<<(E * 8 + 255) / 256, 256, 0, stream>>>(x, vid, cnt, xs, svid, E);

  k_gemm1_max<<<2048, 512, 0, stream>>>(xs, svid, W1, b1, zu, ntiles);

  const int smY = (128 * 264 + 64 * 264) * sizeof(unsigned short);
  hipFuncSetAttribute((const void*)k_ymm,
                      hipFuncAttributeMaxDynamicSharedMemorySize, smY);
  k_ymm<<<782, 256, smY, stream>>>(zu, W2, Y, ntY);

  k_gemm2<<<768, 256, 0, stream>>>(x, vid, W2, Y, out, ntiles);
}